// Round 2
// baseline (60.417 us; speedup 1.0000x reference)
//
#include <hip/hip_runtime.h>
#include <hip/hip_bf16.h>

// TreeCnnLayer: y[b,l,o] = relu( sum_{k=0..3} x[b, idx[l,k], :] . mask[k,:,o] + bias[127] )
// == GEMM: A[131072 x 512] (gathered, fp32->bf16) * Bm[512 x 128] (mask), fp32 out.
//
// Design:
//  - block = 256 thr = 4 waves; per iter: 32 rows x 128 cols, K=512
//  - A staged in LDS (32x512 bf16, XOR-swizzled vs bank conflicts), reg-prefetch 1 iter ahead
//  - mask held as bf16 MFMA B-fragments in VGPRs (2 coltiles x 16 ksteps per wave)
//  - mfma_f32_16x16x32_bf16; wave w owns coltiles {2w, 2w+1}; 2 row-tiles -> 4 acc chains
//
// R1 fix: index_tensor is int32 (JAX default x64-disabled downcasts int64), was read
// as int64 -> garbage gather indices -> device memory fault.

namespace {

constexpr int kNodes = 8192;        // n+1
constexpr int kIn = 128;
constexpr int kOut = 128;
constexpr int kBatch = 16;
constexpr int kRows = 32;           // rows per block-iter
constexpr int kThreads = 256;
constexpr int kGrid = 512;
constexpr int kTotalIters = (kBatch * kNodes) / kRows;  // 4096
constexpr int kItersPerBlock = kTotalIters / kGrid;     // 8

typedef __attribute__((ext_vector_type(8))) short short8;   // 8 bf16 = 4 VGPR (MFMA A/B frag)
typedef __attribute__((ext_vector_type(4))) short short4v;  // 4 bf16 = ds_write_b64
typedef __attribute__((ext_vector_type(4))) float f32x4;    // acc frag / staging load

__device__ __forceinline__ short f2bf(float f) {
  return __builtin_bit_cast(short, __float2bfloat16(f));  // RNE
}

__device__ __forceinline__ int lds_off(int row, int kbyte) {
  // [32 rows][1024 B] with 16B-slot XOR swizzle -> ds_read_b128 conflict-free (G4 / T2)
  return row * 1024 + (kbyte ^ ((row & 7) << 4));
}

__global__ __launch_bounds__(kThreads, 2)
void tree_gemm(const float* __restrict__ x, const float* __restrict__ mask,
               const float* __restrict__ bias, const int* __restrict__ itab,
               float* __restrict__ y) {
  __shared__ __align__(16) unsigned char ldsA[kRows * 512 * 2];  // 32 KiB bf16 A tile

  const int tid  = threadIdx.x;
  const int lane = tid & 63;
  const int wv   = tid >> 6;   // wave 0..3
  const int l15  = lane & 15;
  const int l4   = lane >> 4;  // quarter-wave 0..3

  // ---- B fragments: mask (4,128,128) flat = [512][128]; frag: col=lane&15, k=(lane>>4)*8+e ----
  short8 bfrag[2][16];
  {
    const int krow = l4 * 8;
#pragma unroll
    for (int kk = 0; kk < 16; ++kk) {
      short8 b0, b1;
#pragma unroll
      for (int e = 0; e < 8; ++e) {
        const int k = kk * 32 + krow + e;
        b0[e] = f2bf(mask[k * kOut + wv * 32 + l15]);
        b1[e] = f2bf(mask[k * kOut + wv * 32 + 16 + l15]);
      }
      bfrag[0][kk] = b0;
      bfrag[1][kk] = b1;
    }
  }
  const float blast = bias[kOut - 1];  // reference adds bias[-1] scalar

  // staging geometry: chunk-row cr = row*4+chunk; 32 lanes cover one 512B chunk-row
  const int crBase = wv * 32 + (lane >> 5);  // +2*j, j=0..15
  const int fOff   = (lane & 31) * 4;        // float offset within chunk-row

  f32x4 st[16];  // prefetched gather data (statically indexed only)

  auto loadregs = [&](int iter) {
    const int bb    = iter >> 8;           // 256 iters per batch
    const int lbase = (iter & 255) * kRows;
    const float* xb = x + (size_t)bb * kNodes * kIn;
    const int* ib = itab + (size_t)lbase * 4;  // itab[(lbase+row)*4+chunk] = ib[cr]
#pragma unroll
    for (int j = 0; j < 16; ++j) {
      const int cr = crBase + j * 2;
      const int gi = ib[cr];
      st[j] = *reinterpret_cast<const f32x4*>(xb + (size_t)gi * kIn + fOff);
    }
  };

  auto writelds = [&]() {
#pragma unroll
    for (int j = 0; j < 16; ++j) {
      const int cr    = crBase + j * 2;
      const int row   = cr >> 2;
      const int chunk = cr & 3;
      const int kbyte = chunk * 256 + (lane & 31) * 8;
      short4v pk;
      pk[0] = f2bf(st[j][0]); pk[1] = f2bf(st[j][1]);
      pk[2] = f2bf(st[j][2]); pk[3] = f2bf(st[j][3]);
      *reinterpret_cast<short4v*>(ldsA + lds_off(row, kbyte)) = pk;
    }
  };

  loadregs(blockIdx.x);  // prologue prefetch

  for (int i = 0; i < kItersPerBlock; ++i) {
    const int iter = blockIdx.x + i * kGrid;

    __syncthreads();   // previous compute done reading LDS
    writelds();        // cvt + ds_write current tile
    __syncthreads();   // LDS ready
    if (i + 1 < kItersPerBlock) loadregs(blockIdx.x + (i + 1) * kGrid);  // fly under MFMAs

    f32x4 acc[2][2] = {};  // [rowtile][coltile]
#pragma unroll
    for (int kk = 0; kk < 16; ++kk) {
      const int kbyte = kk * 64 + l4 * 16;  // k_local=(kk*32 + l4*8), bf16 -> bytes
#pragma unroll
      for (int rt = 0; rt < 2; ++rt) {
        const int row = rt * 16 + l15;
        const short8 a =
            *reinterpret_cast<const short8*>(ldsA + lds_off(row, kbyte));
        acc[rt][0] = __builtin_amdgcn_mfma_f32_16x16x32_bf16(a, bfrag[0][kk], acc[rt][0], 0, 0, 0);
        acc[rt][1] = __builtin_amdgcn_mfma_f32_16x16x32_bf16(a, bfrag[1][kk], acc[rt][1], 0, 0, 0);
      }
    }

    // epilogue: D frag layout col=lane&15, row=(lane>>4)*4+r (m89-verified)
    const int bb    = iter >> 8;
    const int lbase = (iter & 255) * kRows;
    float* yb = y + ((size_t)bb * kNodes + lbase) * kOut;
    const int ocol = wv * 32 + l15;
#pragma unroll
    for (int rt = 0; rt < 2; ++rt) {
#pragma unroll
      for (int ct = 0; ct < 2; ++ct) {
#pragma unroll
        for (int r = 0; r < 4; ++r) {
          float v = acc[rt][ct][r] + blast;
          yb[(rt * 16 + l4 * 4 + r) * kOut + ocol + ct * 16] = v > 0.f ? v : 0.f;
        }
      }
    }
  }
}

}  // namespace

extern "C" void kernel_launch(void* const* d_in, const int* in_sizes, int n_in,
                              void* d_out, int out_size, void* d_ws, size_t ws_size,
                              hipStream_t stream) {
  const float* x    = (const float*)d_in[0];
  const float* mask = (const float*)d_in[1];
  const float* bias = (const float*)d_in[2];
  const int*   itab = (const int*)d_in[3];
  float*       y    = (float*)d_out;
  (void)in_sizes; (void)n_in; (void)out_size; (void)d_ws; (void)ws_size;

  tree_gemm<<<dim3(kGrid), dim3(kThreads), 0, stream>>>(x, mask, bias, itab, y);
}